// Round 1
// 193.331 us; speedup vs baseline: 1.0887x; 1.0887x over previous
//
#include <hip/hip_runtime.h>
#include <math.h>

// B=64, S=256, D=1024, T=60, HIST=20. All tensors fp32.
// R7: 4 launches (was 7). conv_e merged into conv grid; kR_lc folded into
// gemm_qw grid; gemm_g+scan fused (G stays in LDS); gemm_qw staged via
// pre-swizzled global_load_lds width=16 (linear LDS dest + XOR'd source,
// XOR'd ds_read — rule #21 both-sides involution).

#define Bn 64
#define Sn 256
#define Dn 1024
#define Tn 60
#define HISTn 20
#define LDK 72
#define K05 1.0512710963760241f   // e^{0.05}
#define EINV 0.36787944117144233f // e^{-1}

typedef __bf16 bf16x8 __attribute__((ext_vector_type(8)));
typedef float f32x4 __attribute__((ext_vector_type(4)));
typedef unsigned short us8 __attribute__((ext_vector_type(8)));

typedef const __attribute__((address_space(1))) unsigned int* gas_u32p;
typedef __attribute__((address_space(3))) unsigned int* las_u32p;

__device__ __forceinline__ void gl16(const unsigned short* g, unsigned short* l){
  __builtin_amdgcn_global_load_lds((gas_u32p)g, (las_u32p)l, 16, 0, 0);
}

__device__ __forceinline__ unsigned short f2bf(float f){
  unsigned int x; __builtin_memcpy(&x,&f,4);
  unsigned int lsb = (x >> 16) & 1u;
  x += 0x7fffu + lsb;
  return (unsigned short)(x >> 16);
}
__device__ __forceinline__ float sigmoidf_(float x){ return 1.0f/(1.0f+expf(-x)); }

// ------ conv: [0,3840) Q->bf16 + rp/ap; [3840,4096) Wq^T; [4096,8192) E part
__global__ __launch_bounds__(256) void conv_fused(
    const float* __restrict__ Q, const float* __restrict__ Wr,
    const float* __restrict__ br, const float* __restrict__ Wa,
    const float* __restrict__ ba, const float* __restrict__ Wq,
    const float* __restrict__ E, const float* __restrict__ Wn,
    float* __restrict__ rp, float* __restrict__ ap,
    unsigned short* __restrict__ Qbf, unsigned short* __restrict__ WT,
    unsigned short* __restrict__ Ebf,
    float* __restrict__ eW1, float* __restrict__ eW2)
{
  int tid = threadIdx.x;
  int bx = blockIdx.x;
  if (bx < Bn*Tn){
    int row = bx;
    float4 x = ((const float4*)(Q + (size_t)row*Dn))[tid];
    float4 a = ((const float4*)Wr)[tid];
    float4 b = ((const float4*)Wa)[tid];
    unsigned short o[4] = {f2bf(x.x), f2bf(x.y), f2bf(x.z), f2bf(x.w)};
    *(uint2*)&Qbf[(size_t)row*Dn + tid*4] = *(uint2*)o;
    float s1 = x.x*a.x + x.y*a.y + x.z*a.z + x.w*a.w;
    float s2 = x.x*b.x + x.y*b.y + x.z*b.z + x.w*b.w;
    for (int off = 32; off; off >>= 1){
      s1 += __shfl_down(s1, off, 64);
      s2 += __shfl_down(s2, off, 64);
    }
    __shared__ float r1[4], r2[4];
    int lane = tid & 63, wv = tid >> 6;
    if (lane == 0){ r1[wv] = s1; r2[wv] = s2; }
    __syncthreads();
    if (tid == 0){
      rp[row] = sigmoidf_(r1[0]+r1[1]+r1[2]+r1[3] + br[0]);
      ap[row] = sigmoidf_(r2[0]+r2[1]+r2[2]+r2[3] + ba[0]);
    }
  } else if (bx < Bn*Tn + 256){
    __shared__ __align__(16) unsigned short Tt[64][LDK];
    int t = bx - Bn*Tn;
    int n0 = (t >> 4)*64, k0 = (t & 15)*64;
    int kl = tid >> 4, nl4 = (tid & 15)*4;
    #pragma unroll
    for (int it = 0; it < 4; it++){
      int k = kl + it*16;
      float4 v = *(const float4*)&Wq[(size_t)(k0+k)*Dn + n0 + nl4];
      Tt[nl4+0][k] = f2bf(v.x); Tt[nl4+1][k] = f2bf(v.y);
      Tt[nl4+2][k] = f2bf(v.z); Tt[nl4+3][k] = f2bf(v.w);
    }
    __syncthreads();
    int nr = tid >> 2, kg = (tid & 3)*16;
    *(us8*)&WT[(size_t)(n0+nr)*Dn + k0+kg]   = *(us8*)&Tt[nr][kg];
    *(us8*)&WT[(size_t)(n0+nr)*Dn + k0+kg+8] = *(us8*)&Tt[nr][kg+8];
  } else {
    // E part: 4 rows per block, one row per 64-lane wave
    int row = (bx - (Bn*Tn + 256))*4 + (tid >> 6);
    int lane = tid & 63;
    const float* er = E + (size_t)row*Dn;
    unsigned short* ebr = Ebf + (size_t)row*Dn;
    float d1 = 0.f, d2 = 0.f;
    #pragma unroll
    for (int c = 0; c < 4; c++){
      int idx = c*64 + lane;
      float4 v = ((const float4*)er)[idx];
      float4 w1 = ((const float4*)Wn)[idx];
      float4 w2 = ((const float4*)(Wn + Dn))[idx];
      unsigned short o[4] = {f2bf(v.x), f2bf(v.y), f2bf(v.z), f2bf(v.w)};
      ((uint2*)ebr)[idx] = *(uint2*)o;
      d1 += v.x*w1.x + v.y*w1.y + v.z*w1.z + v.w*w1.w;
      d2 += v.x*w2.x + v.y*w2.y + v.z*w2.z + v.w*w2.w;
    }
    #pragma unroll
    for (int off = 32; off; off >>= 1){
      d1 += __shfl_down(d1, off, 64);
      d2 += __shfl_down(d2, off, 64);
    }
    if (lane == 0){ eW1[row] = d1; eW2[row] = d2; }
  }
}

// ------ gemm_qw_kr: [0,960) QW = Q @ Wq via gload_lds; [960,1024) kR_lc ----
__global__ __launch_bounds__(256) void gemm_qw_kr(
    const unsigned short* __restrict__ Qbf,
    const unsigned short* __restrict__ WT,
    const float* __restrict__ At,
    const float* __restrict__ eW2,
    unsigned short* __restrict__ QWbf,
    float* __restrict__ lc)
{
  int tid = threadIdx.x;
  if (blockIdx.x < (Bn*Tn/64)*(Dn/64)){
    // 64x64 tile, BK=64, 4 waves each 16 m-rows x 64 n-cols.
    // LDS linear [64][64] bf16, staged with global_load_lds width 16.
    // Swizzle involution: source col ((l&7)^(l>>3))*8, read col ^ (row&7)*8.
    __shared__ __align__(16) unsigned short As[64*64], Bs[64*64];
    int bx = blockIdx.x;
    int m0 = (bx >> 4) * 64, n0 = (bx & 15) * 64;
    int lane = tid & 63, wave = tid >> 6;
    int quad = lane >> 4, l16 = lane & 15;
    f32x4 acc[4];
    #pragma unroll
    for (int nt=0;nt<4;nt++)
      #pragma unroll
      for (int r=0;r<4;r++) acc[nt][r]=0.f;
    // staging: 8 chunks of 1024B (8 rows each); wave handles chunks 2w,2w+1
    int c0 = wave*2;
    int srow = c0*8 + (lane >> 3);
    int scol = ((lane & 7) ^ (lane >> 3)) * 8;
    const unsigned short* gA0 = Qbf + (size_t)(m0 + srow)*Dn + scol;
    const unsigned short* gA1 = gA0 + 8*Dn;
    const unsigned short* gB0 = WT  + (size_t)(n0 + srow)*Dn + scol;
    const unsigned short* gB1 = gB0 + 8*Dn;
    unsigned short* lA0 = &As[c0*512];
    unsigned short* lA1 = &As[c0*512 + 512];
    unsigned short* lB0 = &Bs[c0*512];
    unsigned short* lB1 = &Bs[c0*512 + 512];
    int mrow = wave*16 + l16;
    for (int k0 = 0; k0 < Dn; k0 += 64){
      gl16(gA0 + k0, lA0);
      gl16(gA1 + k0, lA1);
      gl16(gB0 + k0, lB0);
      gl16(gB1 + k0, lB1);
      __syncthreads();
      #pragma unroll
      for (int kk = 0; kk < 2; kk++){
        bf16x8 a = *(const bf16x8*)&As[ mrow*64 + ((kk*32 + quad*8) ^ ((mrow&7)*8)) ];
        #pragma unroll
        for (int nt=0;nt<4;nt++){
          int nrow = nt*16 + l16;
          bf16x8 bb = *(const bf16x8*)&Bs[ nrow*64 + ((kk*32 + quad*8) ^ ((nrow&7)*8)) ];
          acc[nt] = __builtin_amdgcn_mfma_f32_16x16x32_bf16(a, bb, acc[nt], 0, 0, 0);
        }
      }
      __syncthreads();
    }
    #pragma unroll
    for (int nt=0;nt<4;nt++)
      #pragma unroll
      for (int r=0;r<4;r++){
        int m = m0 + wave*16 + quad*4 + r;
        int n = n0 + nt*16 + l16;
        QWbf[(size_t)m*Dn + n] = f2bf(acc[nt][r]);
      }
  } else {
    int b = blockIdx.x - (Bn*Tn/64)*(Dn/64);
    int lane = tid & 63, wv = tid >> 6;
    __shared__ float Rsh[Tn];
    float4 e2v = ((const float4*)(eW2 + (size_t)b*Sn))[lane];
    const float* at_b = At + (size_t)b*Tn*Sn;
    #pragma unroll
    for (int w = 0; w < 15; w++){
      int j = wv + w*4;
      float4 a4 = ((const float4*)(at_b + (size_t)j*Sn))[lane];
      float v = a4.x*e2v.x + a4.y*e2v.y + a4.z*e2v.z + a4.w*e2v.w;
      #pragma unroll
      for (int off = 32; off; off >>= 1) v += __shfl_down(v, off, 64);
      if (lane == 0) Rsh[j] = v;
    }
    __syncthreads();
    if (tid < Tn){
      int i = tid;
      int j0 = (i - HISTn + 1 > 0) ? i - HISTn + 1 : 0;
      float num = 0.f, den = 0.f;
      float wj = 1.f;
      for (int j = 0; j <= i; j++){
        wj *= K05;
        if (j >= j0){ num += wj * Rsh[j]; den += wj; }
      }
      lc[b*Tn + i] = num / den;
    }
  }
}

// ------ g_scan: fused G-GEMM (60x64 tile, K=1024) + scalar scan ------------
__global__ __launch_bounds__(256) void g_scan(
    const unsigned short* __restrict__ QWbf,
    const unsigned short* __restrict__ Ebf,
    const float* __restrict__ At,
    const float* __restrict__ rp,
    const float* __restrict__ ap,
    const float* __restrict__ eW1,
    const float* __restrict__ lc,
    const float* __restrict__ bnp,
    unsigned short* __restrict__ Pbf)
{
  __shared__ __align__(16) unsigned short As[64][LDK], Bs[64][LDK];
  __shared__ __align__(16) float AtL[Tn][64], GL[Tn][64];
  __shared__ float lcs[Tn], rps[Tn], aps[Tn];
  int b = blockIdx.x, s0 = blockIdx.y * 64;
  int tid = threadIdx.x, lane = tid & 63, wave = tid >> 6;
  int quad = lane >> 4, l16 = lane & 15;

  // stage At slab + per-step scalars (consumed after the GEMM barrier)
  const float* at_b = At + (size_t)b*Tn*Sn + s0;
  #pragma unroll
  for (int it = 0; it < 4; it++){
    int r = it*16 + (tid >> 4);
    if (r < Tn){
      int c4 = (tid & 15)*4;
      *(float4*)&AtL[r][c4] = *(const float4*)&at_b[(size_t)r*Sn + c4];
    }
  }
  if (tid < Tn){
    lcs[tid] = lc[b*Tn + tid];
    rps[tid] = rp[b*Tn + tid];
    aps[tid] = ap[b*Tn + tid];
  }

  f32x4 acc[4];
  #pragma unroll
  for (int nt=0;nt<4;nt++)
    #pragma unroll
    for (int r=0;r<4;r++) acc[nt][r]=0.f;
  int sr = tid >> 2, sk = (tid & 3)*16;
  const unsigned short* aRow = QWbf + ((size_t)(b*Tn + sr))*Dn;
  const unsigned short* bRow = Ebf  + ((size_t)(b*Sn + s0 + sr))*Dn;
  for (int k0 = 0; k0 < Dn; k0 += 64){
    if (sr < Tn){
      *(us8*)&As[sr][sk]   = *(const us8*)&aRow[k0+sk];
      *(us8*)&As[sr][sk+8] = *(const us8*)&aRow[k0+sk+8];
    } else {
      us8 z = (us8)0;
      *(us8*)&As[sr][sk] = z; *(us8*)&As[sr][sk+8] = z;
    }
    *(us8*)&Bs[sr][sk]   = *(const us8*)&bRow[k0+sk];
    *(us8*)&Bs[sr][sk+8] = *(const us8*)&bRow[k0+sk+8];
    __syncthreads();
    #pragma unroll
    for (int kk = 0; kk < 64; kk += 32){
      bf16x8 a = *(const bf16x8*)&As[wave*16 + l16][kk + quad*8];
      #pragma unroll
      for (int nt=0;nt<4;nt++){
        bf16x8 bb = *(const bf16x8*)&Bs[nt*16 + l16][kk + quad*8];
        acc[nt] = __builtin_amdgcn_mfma_f32_16x16x32_bf16(a, bb, acc[nt], 0, 0, 0);
      }
    }
    __syncthreads();
  }
  // drop accumulators into LDS: GL[t][s_local]
  #pragma unroll
  for (int nt=0;nt<4;nt++)
    #pragma unroll
    for (int r=0;r<4;r++){
      int t = wave*16 + quad*4 + r;
      if (t < Tn) GL[t][nt*16 + l16] = acc[nt][r];
    }
  __syncthreads();

  if (tid < 64){
    int s = s0 + tid;
    float M = (s < 50) ? (1.0f - (s+1)/50.0f) : 0.0f;
    float A = M;
    float bnv = bnp[0];
    float e1 = eW1[b*Sn + s];
    unsigned short* P_b = Pbf + (size_t)b*Tn*Sn + s;
    float num_a = 0.f, num_q = 0.f, den = 0.f, wi = 1.f;
    #pragma unroll
    for (int i = 0; i < Tn; i++){
      wi *= K05;
      float a_new = AtL[i][tid];
      float g_new = GL[i][tid];
      num_a += wi * a_new;
      num_q += wi * g_new;
      den   += wi;
      if (i >= HISTn){
        float wo = wi * EINV;
        num_a -= wo * AtL[i-HISTn][tid];
        num_q -= wo * GL[i-HISTn][tid];
        den   -= wo;
      }
      float inv = 1.0f / den;
      float aw = num_a * inv;
      float qd = num_q * inv;
      P_b[(size_t)i*Sn] = f2bf(a_new * M);   // sel uses mem at step ENTRY
      float sim = sigmoidf_(M * qd);
      float nxt = sigmoidf_(e1 + lcs[i] + bnv);
      M = M * (1.0f - rps[i] * aw * sim);
      float g = (1.0f - A) * aps[i] * nxt;
      M += g; A += g;
    }
  }
}

// ------ gemm_sels: out[b] = P[b](TxS) @ Ebf[b](SxD), fp32 out ---------------
__global__ __launch_bounds__(256) void gemm_sels(
    const unsigned short* __restrict__ Pbf,
    const unsigned short* __restrict__ Ebf,
    float* __restrict__ out)
{
  __shared__ __align__(16) unsigned short As[64][LDK], Bs[64][LDK];
  int b = blockIdx.x, n0 = blockIdx.y*64;   // n over D
  int tid = threadIdx.x, lane = tid & 63, wave = tid >> 6;
  int quad = lane >> 4, l16 = lane & 15;
  f32x4 acc[4];
  #pragma unroll
  for (int nt=0;nt<4;nt++)
    #pragma unroll
    for (int r=0;r<4;r++) acc[nt][r]=0.f;
  int sr = tid >> 2, sk = (tid & 3)*16;
  for (int k0 = 0; k0 < Sn; k0 += 64){
    if (sr < Tn){
      *(us8*)&As[sr][sk]   = *(const us8*)&Pbf[((size_t)(b*Tn + sr))*Sn + k0+sk];
      *(us8*)&As[sr][sk+8] = *(const us8*)&Pbf[((size_t)(b*Tn + sr))*Sn + k0+sk+8];
    } else {
      us8 z = (us8)0;
      *(us8*)&As[sr][sk] = z; *(us8*)&As[sr][sk+8] = z;
    }
    {
      const unsigned short* ep = &Ebf[((size_t)(b*Sn + k0 + sr))*Dn + n0 + sk];
      us8 e0 = *(const us8*)ep;
      us8 e1 = *(const us8*)(ep + 8);
      #pragma unroll
      for (int j=0;j<8;j++){
        Bs[sk+j][sr]   = e0[j];
        Bs[sk+8+j][sr] = e1[j];
      }
    }
    __syncthreads();
    #pragma unroll
    for (int kk = 0; kk < 64; kk += 32){
      bf16x8 a = *(const bf16x8*)&As[wave*16 + l16][kk + quad*8];
      #pragma unroll
      for (int nt=0;nt<4;nt++){
        bf16x8 bb = *(const bf16x8*)&Bs[nt*16 + l16][kk + quad*8];
        acc[nt] = __builtin_amdgcn_mfma_f32_16x16x32_bf16(a, bb, acc[nt], 0, 0, 0);
      }
    }
    __syncthreads();
  }
  #pragma unroll
  for (int nt=0;nt<4;nt++)
    #pragma unroll
    for (int r=0;r<4;r++){
      int t = wave*16 + quad*4 + r;
      int d = n0 + nt*16 + l16;
      if (t < Tn) out[((size_t)(b*Tn + t))*Dn + d] = acc[nt][r];
    }
}

extern "C" void kernel_launch(void* const* d_in, const int* in_sizes, int n_in,
                              void* d_out, int out_size, void* d_ws, size_t ws_size,
                              hipStream_t stream)
{
  const float* E  = (const float*)d_in[0];
  const float* Q  = (const float*)d_in[1];
  const float* At = (const float*)d_in[2];
  const float* Wr = (const float*)d_in[3];
  const float* br = (const float*)d_in[4];
  const float* Wa = (const float*)d_in[5];
  const float* ba = (const float*)d_in[6];
  const float* Wq = (const float*)d_in[7];
  const float* Wn = (const float*)d_in[8];
  const float* bnp= (const float*)d_in[9];

  char* ws = (char*)d_ws;
  float* rp  = (float*)ws; ws += (size_t)Bn*Tn*4;
  float* ap  = (float*)ws; ws += (size_t)Bn*Tn*4;
  float* eW1 = (float*)ws; ws += (size_t)Bn*Sn*4;
  float* eW2 = (float*)ws; ws += (size_t)Bn*Sn*4;
  float* lcb = (float*)ws; ws += (size_t)Bn*Tn*4;
  unsigned short* Qbf  = (unsigned short*)ws; ws += (size_t)Bn*Tn*Dn*2;  // 7.86 MB
  unsigned short* WT   = (unsigned short*)ws; ws += (size_t)Dn*Dn*2;     // 2.1 MB
  unsigned short* QWbf = (unsigned short*)ws; ws += (size_t)Bn*Tn*Dn*2;  // 7.86 MB
  unsigned short* Ebf  = (unsigned short*)ws; ws += (size_t)Bn*Sn*Dn*2;  // 33.6 MB
  unsigned short* Pbf = (unsigned short*)ws; ws += (size_t)Bn*Tn*Sn*2;   // 1.97 MB

  conv_fused<<<Bn*Tn + 256 + Bn*Sn/4, 256, 0, stream>>>(
      Q, Wr, br, Wa, ba, Wq, E, Wn, rp, ap, Qbf, WT, Ebf, eW1, eW2);
  gemm_qw_kr<<<(Bn*Tn/64)*(Dn/64) + Bn, 256, 0, stream>>>(
      Qbf, WT, At, eW2, QWbf, lcb);
  g_scan<<<dim3(Bn, Sn/64), 256, 0, stream>>>(
      QWbf, Ebf, At, rp, ap, eW1, lcb, bnp, Pbf);
  gemm_sels<<<dim3(Bn, Dn/64), 256, 0, stream>>>(Pbf, Ebf, (float*)d_out);
}

// Round 2
// 184.089 us; speedup vs baseline: 1.1434x; 1.0502x over previous
//
#include <hip/hip_runtime.h>
#include <math.h>

// B=64, S=256, D=1024, T=60, HIST=20. All tensors fp32.
// R8: all three GEMM K-loops converted to 2-phase double-buffered pipelines
// (T3 minimal recipe: stage(next) -> compute(cur) -> ONE barrier/step, load
// latency hidden under MFMA). gemm_qw keeps gload_lds w16 + swizzle involution
// and gains an XCD-bijective block swizzle (960%8==0).

#define Bn 64
#define Sn 256
#define Dn 1024
#define Tn 60
#define HISTn 20
#define LDK 72
#define K05 1.0512710963760241f   // e^{0.05}
#define EINV 0.36787944117144233f // e^{-1}

typedef __bf16 bf16x8 __attribute__((ext_vector_type(8)));
typedef float f32x4 __attribute__((ext_vector_type(4)));
typedef unsigned short us8 __attribute__((ext_vector_type(8)));

typedef const __attribute__((address_space(1))) unsigned int* gas_u32p;
typedef __attribute__((address_space(3))) unsigned int* las_u32p;

__device__ __forceinline__ void gl16(const unsigned short* g, unsigned short* l){
  __builtin_amdgcn_global_load_lds((gas_u32p)g, (las_u32p)l, 16, 0, 0);
}

__device__ __forceinline__ unsigned short f2bf(float f){
  unsigned int x; __builtin_memcpy(&x,&f,4);
  unsigned int lsb = (x >> 16) & 1u;
  x += 0x7fffu + lsb;
  return (unsigned short)(x >> 16);
}
__device__ __forceinline__ float sigmoidf_(float x){ return 1.0f/(1.0f+expf(-x)); }

// ------ conv: [0,3840) Q->bf16 + rp/ap; [3840,4096) Wq^T; [4096,8192) E part
__global__ __launch_bounds__(256) void conv_fused(
    const float* __restrict__ Q, const float* __restrict__ Wr,
    const float* __restrict__ br, const float* __restrict__ Wa,
    const float* __restrict__ ba, const float* __restrict__ Wq,
    const float* __restrict__ E, const float* __restrict__ Wn,
    float* __restrict__ rp, float* __restrict__ ap,
    unsigned short* __restrict__ Qbf, unsigned short* __restrict__ WT,
    unsigned short* __restrict__ Ebf,
    float* __restrict__ eW1, float* __restrict__ eW2)
{
  int tid = threadIdx.x;
  int bx = blockIdx.x;
  if (bx < Bn*Tn){
    int row = bx;
    float4 x = ((const float4*)(Q + (size_t)row*Dn))[tid];
    float4 a = ((const float4*)Wr)[tid];
    float4 b = ((const float4*)Wa)[tid];
    unsigned short o[4] = {f2bf(x.x), f2bf(x.y), f2bf(x.z), f2bf(x.w)};
    *(uint2*)&Qbf[(size_t)row*Dn + tid*4] = *(uint2*)o;
    float s1 = x.x*a.x + x.y*a.y + x.z*a.z + x.w*a.w;
    float s2 = x.x*b.x + x.y*b.y + x.z*b.z + x.w*b.w;
    for (int off = 32; off; off >>= 1){
      s1 += __shfl_down(s1, off, 64);
      s2 += __shfl_down(s2, off, 64);
    }
    __shared__ float r1[4], r2[4];
    int lane = tid & 63, wv = tid >> 6;
    if (lane == 0){ r1[wv] = s1; r2[wv] = s2; }
    __syncthreads();
    if (tid == 0){
      rp[row] = sigmoidf_(r1[0]+r1[1]+r1[2]+r1[3] + br[0]);
      ap[row] = sigmoidf_(r2[0]+r2[1]+r2[2]+r2[3] + ba[0]);
    }
  } else if (bx < Bn*Tn + 256){
    __shared__ __align__(16) unsigned short Tt[64][LDK];
    int t = bx - Bn*Tn;
    int n0 = (t >> 4)*64, k0 = (t & 15)*64;
    int kl = tid >> 4, nl4 = (tid & 15)*4;
    #pragma unroll
    for (int it = 0; it < 4; it++){
      int k = kl + it*16;
      float4 v = *(const float4*)&Wq[(size_t)(k0+k)*Dn + n0 + nl4];
      Tt[nl4+0][k] = f2bf(v.x); Tt[nl4+1][k] = f2bf(v.y);
      Tt[nl4+2][k] = f2bf(v.z); Tt[nl4+3][k] = f2bf(v.w);
    }
    __syncthreads();
    int nr = tid >> 2, kg = (tid & 3)*16;
    *(us8*)&WT[(size_t)(n0+nr)*Dn + k0+kg]   = *(us8*)&Tt[nr][kg];
    *(us8*)&WT[(size_t)(n0+nr)*Dn + k0+kg+8] = *(us8*)&Tt[nr][kg+8];
  } else {
    // E part: 4 rows per block, one row per 64-lane wave
    int row = (bx - (Bn*Tn + 256))*4 + (tid >> 6);
    int lane = tid & 63;
    const float* er = E + (size_t)row*Dn;
    unsigned short* ebr = Ebf + (size_t)row*Dn;
    float d1 = 0.f, d2 = 0.f;
    #pragma unroll
    for (int c = 0; c < 4; c++){
      int idx = c*64 + lane;
      float4 v = ((const float4*)er)[idx];
      float4 w1 = ((const float4*)Wn)[idx];
      float4 w2 = ((const float4*)(Wn + Dn))[idx];
      unsigned short o[4] = {f2bf(v.x), f2bf(v.y), f2bf(v.z), f2bf(v.w)};
      ((uint2*)ebr)[idx] = *(uint2*)o;
      d1 += v.x*w1.x + v.y*w1.y + v.z*w1.z + v.w*w1.w;
      d2 += v.x*w2.x + v.y*w2.y + v.z*w2.z + v.w*w2.w;
    }
    #pragma unroll
    for (int off = 32; off; off >>= 1){
      d1 += __shfl_down(d1, off, 64);
      d2 += __shfl_down(d2, off, 64);
    }
    if (lane == 0){ eW1[row] = d1; eW2[row] = d2; }
  }
}

// ------ gemm_qw_kr: [0,960) QW = Q @ Wq (2-phase gload_lds); [960,1024) kR_lc
__global__ __launch_bounds__(256) void gemm_qw_kr(
    const unsigned short* __restrict__ Qbf,
    const unsigned short* __restrict__ WT,
    const float* __restrict__ At,
    const float* __restrict__ eW2,
    unsigned short* __restrict__ QWbf,
    float* __restrict__ lc)
{
  int tid = threadIdx.x;
  if (blockIdx.x < (Bn*Tn/64)*(Dn/64)){
    // 64x64 tile, BK=64, double-buffered global_load_lds (w16).
    // Swizzle involution: source col ((l&7)^(l>>3))*8, read col ^ (row&7)*8.
    __shared__ __align__(16) unsigned short As0_[64*64], Bs0_[64*64];
    __shared__ __align__(16) unsigned short As1_[64*64], Bs1_[64*64];
    // XCD-bijective swizzle: 960 blocks, 960%8==0, chunk=120 per XCD.
    int bx = (blockIdx.x & 7)*120 + (blockIdx.x >> 3);
    int m0 = (bx >> 4) * 64, n0 = (bx & 15) * 64;
    int lane = tid & 63, wave = tid >> 6;
    int quad = lane >> 4, l16 = lane & 15;
    f32x4 acc[4];
    #pragma unroll
    for (int nt=0;nt<4;nt++)
      #pragma unroll
      for (int r=0;r<4;r++) acc[nt][r]=0.f;
    int c0 = wave*2;
    int srow = c0*8 + (lane >> 3);
    int scol = ((lane & 7) ^ (lane >> 3)) * 8;
    const unsigned short* gA0 = Qbf + (size_t)(m0 + srow)*Dn + scol;
    const unsigned short* gA1 = gA0 + 8*Dn;
    const unsigned short* gB0 = WT  + (size_t)(n0 + srow)*Dn + scol;
    const unsigned short* gB1 = gB0 + 8*Dn;
    int mrow = wave*16 + l16;

    #define STAGE_QW(K, A_, B_) { \
      gl16(gA0 + (K), &A_[c0*512]);       \
      gl16(gA1 + (K), &A_[c0*512 + 512]); \
      gl16(gB0 + (K), &B_[c0*512]);       \
      gl16(gB1 + (K), &B_[c0*512 + 512]); }
    #define COMP_QW(A_, B_) { \
      _Pragma("unroll") \
      for (int kk = 0; kk < 2; kk++){ \
        bf16x8 a = *(const bf16x8*)&A_[ mrow*64 + ((kk*32 + quad*8) ^ ((mrow&7)*8)) ]; \
        _Pragma("unroll") \
        for (int nt=0;nt<4;nt++){ \
          int nrow = nt*16 + l16; \
          bf16x8 bb = *(const bf16x8*)&B_[ nrow*64 + ((kk*32 + quad*8) ^ ((nrow&7)*8)) ]; \
          acc[nt] = __builtin_amdgcn_mfma_f32_16x16x32_bf16(a, bb, acc[nt], 0, 0, 0); \
        } \
      } }

    STAGE_QW(0, As0_, Bs0_);
    __syncthreads();
    #pragma unroll
    for (int k0 = 0; k0 < Dn; k0 += 128){
      STAGE_QW(k0+64, As1_, Bs1_);          // k0+64 <= 960 < Dn always
      COMP_QW(As0_, Bs0_);
      __syncthreads();                       // drains vmcnt + lgkm, barrier
      if (k0+128 < Dn) STAGE_QW(k0+128, As0_, Bs0_);
      COMP_QW(As1_, Bs1_);
      __syncthreads();
    }
    #undef STAGE_QW
    #undef COMP_QW

    #pragma unroll
    for (int nt=0;nt<4;nt++)
      #pragma unroll
      for (int r=0;r<4;r++){
        int m = m0 + wave*16 + quad*4 + r;
        int n = n0 + nt*16 + l16;
        QWbf[(size_t)m*Dn + n] = f2bf(acc[nt][r]);
      }
  } else {
    int b = blockIdx.x - (Bn*Tn/64)*(Dn/64);
    int lane = tid & 63, wv = tid >> 6;
    __shared__ float Rsh[Tn];
    float4 e2v = ((const float4*)(eW2 + (size_t)b*Sn))[lane];
    const float* at_b = At + (size_t)b*Tn*Sn;
    #pragma unroll
    for (int w = 0; w < 15; w++){
      int j = wv + w*4;
      float4 a4 = ((const float4*)(at_b + (size_t)j*Sn))[lane];
      float v = a4.x*e2v.x + a4.y*e2v.y + a4.z*e2v.z + a4.w*e2v.w;
      #pragma unroll
      for (int off = 32; off; off >>= 1) v += __shfl_down(v, off, 64);
      if (lane == 0) Rsh[j] = v;
    }
    __syncthreads();
    if (tid < Tn){
      int i = tid;
      int j0 = (i - HISTn + 1 > 0) ? i - HISTn + 1 : 0;
      float num = 0.f, den = 0.f;
      float wj = 1.f;
      for (int j = 0; j <= i; j++){
        wj *= K05;
        if (j >= j0){ num += wj * Rsh[j]; den += wj; }
      }
      lc[b*Tn + i] = num / den;
    }
  }
}

// ------ g_scan: fused G-GEMM (60x64 tile, K=1024, 2-phase) + scalar scan ----
__global__ __launch_bounds__(256) void g_scan(
    const unsigned short* __restrict__ QWbf,
    const unsigned short* __restrict__ Ebf,
    const float* __restrict__ At,
    const float* __restrict__ rp,
    const float* __restrict__ ap,
    const float* __restrict__ eW1,
    const float* __restrict__ lc,
    const float* __restrict__ bnp,
    unsigned short* __restrict__ Pbf)
{
  __shared__ __align__(16) unsigned short As0_[64][LDK], Bs0_[64][LDK];
  __shared__ __align__(16) unsigned short As1_[64][LDK], Bs1_[64][LDK];
  __shared__ __align__(16) float AtL[Tn][64], GL[Tn][64];
  __shared__ float lcs[Tn], rps[Tn], aps[Tn];
  int b = blockIdx.x, s0 = blockIdx.y * 64;
  int tid = threadIdx.x, lane = tid & 63, wave = tid >> 6;
  int quad = lane >> 4, l16 = lane & 15;

  // stage At slab + per-step scalars (consumed after the GEMM barriers)
  const float* at_b = At + (size_t)b*Tn*Sn + s0;
  #pragma unroll
  for (int it = 0; it < 4; it++){
    int r = it*16 + (tid >> 4);
    if (r < Tn){
      int c4 = (tid & 15)*4;
      *(float4*)&AtL[r][c4] = *(const float4*)&at_b[(size_t)r*Sn + c4];
    }
  }
  if (tid < Tn){
    lcs[tid] = lc[b*Tn + tid];
    rps[tid] = rp[b*Tn + tid];
    aps[tid] = ap[b*Tn + tid];
  }

  f32x4 acc[4];
  #pragma unroll
  for (int nt=0;nt<4;nt++)
    #pragma unroll
    for (int r=0;r<4;r++) acc[nt][r]=0.f;
  int sr = tid >> 2, sk = (tid & 3)*16;
  const unsigned short* aRow = QWbf + ((size_t)(b*Tn + sr))*Dn;
  const unsigned short* bRow = Ebf  + ((size_t)(b*Sn + s0 + sr))*Dn;

  #define LOADR(K, ra0, ra1, rb0, rb1) { \
    if (sr < Tn){ ra0 = *(const us8*)&aRow[(K)+sk]; ra1 = *(const us8*)&aRow[(K)+sk+8]; } \
    else { ra0 = (us8)0; ra1 = (us8)0; } \
    rb0 = *(const us8*)&bRow[(K)+sk]; rb1 = *(const us8*)&bRow[(K)+sk+8]; }
  #define STORER(A_, B_, ra0, ra1, rb0, rb1) { \
    *(us8*)&A_[sr][sk]   = ra0; *(us8*)&A_[sr][sk+8] = ra1; \
    *(us8*)&B_[sr][sk]   = rb0; *(us8*)&B_[sr][sk+8] = rb1; }
  #define COMP_G(A_, B_) { \
    _Pragma("unroll") \
    for (int kk = 0; kk < 64; kk += 32){ \
      bf16x8 a = *(const bf16x8*)&A_[wave*16 + l16][kk + quad*8]; \
      _Pragma("unroll") \
      for (int nt=0;nt<4;nt++){ \
        bf16x8 bb = *(const bf16x8*)&B_[nt*16 + l16][kk + quad*8]; \
        acc[nt] = __builtin_amdgcn_mfma_f32_16x16x32_bf16(a, bb, acc[nt], 0, 0, 0); \
      } \
    } }

  us8 pa0, pa1, pb0, pb1, qa0, qa1, qb0, qb1;
  LOADR(0, pa0, pa1, pb0, pb1);
  STORER(As0_, Bs0_, pa0, pa1, pb0, pb1);
  for (int k0 = 0; k0 < Dn; k0 += 128){
    LOADR(k0+64, qa0, qa1, qb0, qb1);       // k0+64 <= 960 < Dn always
    __syncthreads();
    COMP_G(As0_, Bs0_);
    STORER(As1_, Bs1_, qa0, qa1, qb0, qb1);
    if (k0+128 < Dn) LOADR(k0+128, pa0, pa1, pb0, pb1);
    __syncthreads();
    COMP_G(As1_, Bs1_);
    if (k0+128 < Dn) STORER(As0_, Bs0_, pa0, pa1, pb0, pb1);
  }
  #undef LOADR
  #undef STORER
  #undef COMP_G

  // drop accumulators into LDS: GL[t][s_local]
  #pragma unroll
  for (int nt=0;nt<4;nt++)
    #pragma unroll
    for (int r=0;r<4;r++){
      int t = wave*16 + quad*4 + r;
      if (t < Tn) GL[t][nt*16 + l16] = acc[nt][r];
    }
  __syncthreads();

  if (tid < 64){
    int s = s0 + tid;
    float M = (s < 50) ? (1.0f - (s+1)/50.0f) : 0.0f;
    float A = M;
    float bnv = bnp[0];
    float e1 = eW1[b*Sn + s];
    unsigned short* P_b = Pbf + (size_t)b*Tn*Sn + s;
    float num_a = 0.f, num_q = 0.f, den = 0.f, wi = 1.f;
    #pragma unroll
    for (int i = 0; i < Tn; i++){
      wi *= K05;
      float a_new = AtL[i][tid];
      float g_new = GL[i][tid];
      num_a += wi * a_new;
      num_q += wi * g_new;
      den   += wi;
      if (i >= HISTn){
        float wo = wi * EINV;
        num_a -= wo * AtL[i-HISTn][tid];
        num_q -= wo * GL[i-HISTn][tid];
        den   -= wo;
      }
      float inv = 1.0f / den;
      float aw = num_a * inv;
      float qd = num_q * inv;
      P_b[(size_t)i*Sn] = f2bf(a_new * M);   // sel uses mem at step ENTRY
      float sim = sigmoidf_(M * qd);
      float nxt = sigmoidf_(e1 + lcs[i] + bnv);
      M = M * (1.0f - rps[i] * aw * sim);
      float g = (1.0f - A) * aps[i] * nxt;
      M += g; A += g;
    }
  }
}

// ------ gemm_sels: out[b] = P[b](TxS) @ Ebf[b](SxD), fp32 out, 2-phase ------
__global__ __launch_bounds__(256) void gemm_sels(
    const unsigned short* __restrict__ Pbf,
    const unsigned short* __restrict__ Ebf,
    float* __restrict__ out)
{
  __shared__ __align__(16) unsigned short As0_[64][LDK], Bs0_[64][LDK];
  __shared__ __align__(16) unsigned short As1_[64][LDK], Bs1_[64][LDK];
  int b = blockIdx.x, n0 = blockIdx.y*64;   // n over D
  int tid = threadIdx.x, lane = tid & 63, wave = tid >> 6;
  int quad = lane >> 4, l16 = lane & 15;
  f32x4 acc[4];
  #pragma unroll
  for (int nt=0;nt<4;nt++)
    #pragma unroll
    for (int r=0;r<4;r++) acc[nt][r]=0.f;
  int sr = tid >> 2, sk = (tid & 3)*16;

  #define SLOAD(K, ra0, ra1, re0, re1) { \
    if (sr < Tn){ \
      const unsigned short* pp = &Pbf[((size_t)(b*Tn + sr))*Sn + (K)+sk]; \
      ra0 = *(const us8*)pp; ra1 = *(const us8*)(pp+8); \
    } else { ra0 = (us8)0; ra1 = (us8)0; } \
    const unsigned short* ep = &Ebf[((size_t)(b*Sn + (K) + sr))*Dn + n0 + sk]; \
    re0 = *(const us8*)ep; re1 = *(const us8*)(ep + 8); }
  #define SSTORE(A_, B_, ra0, ra1, re0, re1) { \
    *(us8*)&A_[sr][sk]   = ra0; *(us8*)&A_[sr][sk+8] = ra1; \
    _Pragma("unroll") \
    for (int j=0;j<8;j++){ \
      B_[sk+j][sr]   = re0[j]; \
      B_[sk+8+j][sr] = re1[j]; } }
  #define COMP_S(A_, B_) { \
    _Pragma("unroll") \
    for (int kk = 0; kk < 64; kk += 32){ \
      bf16x8 a = *(const bf16x8*)&A_[wave*16 + l16][kk + quad*8]; \
      _Pragma("unroll") \
      for (int nt=0;nt<4;nt++){ \
        bf16x8 bb = *(const bf16x8*)&B_[nt*16 + l16][kk + quad*8]; \
        acc[nt] = __builtin_amdgcn_mfma_f32_16x16x32_bf16(a, bb, acc[nt], 0, 0, 0); \
      } \
    } }

  us8 pa0, pa1, pe0, pe1, qa0, qa1, qe0, qe1;
  SLOAD(0, pa0, pa1, pe0, pe1);
  SSTORE(As0_, Bs0_, pa0, pa1, pe0, pe1);
  #pragma unroll
  for (int k0 = 0; k0 < Sn; k0 += 128){
    SLOAD(k0+64, qa0, qa1, qe0, qe1);       // k0+64 <= 192 < Sn always
    __syncthreads();
    COMP_S(As0_, Bs0_);
    SSTORE(As1_, Bs1_, qa0, qa1, qe0, qe1);
    if (k0+128 < Sn) SLOAD(k0+128, pa0, pa1, pe0, pe1);
    __syncthreads();
    COMP_S(As1_, Bs1_);
    if (k0+128 < Sn) SSTORE(As0_, Bs0_, pa0, pa1, pe0, pe1);
  }
  #undef SLOAD
  #undef SSTORE
  #undef COMP_S

  #pragma unroll
  for (int nt=0;nt<4;nt++)
    #pragma unroll
    for (int r=0;r<4;r++){
      int t = wave*16 + quad*4 + r;
      int d = n0 + nt*16 + l16;
      if (t < Tn) out[((size_t)(b*Tn + t))*Dn + d] = acc[nt][r];
    }
}

extern "C" void kernel_launch(void* const* d_in, const int* in_sizes, int n_in,
                              void* d_out, int out_size, void* d_ws, size_t ws_size,
                              hipStream_t stream)
{
  const float* E  = (const float*)d_in[0];
  const float* Q  = (const float*)d_in[1];
  const float* At = (const float*)d_in[2];
  const float* Wr = (const float*)d_in[3];
  const float* br = (const float*)d_in[4];
  const float* Wa = (const float*)d_in[5];
  const float* ba = (const float*)d_in[6];
  const float* Wq = (const float*)d_in[7];
  const float* Wn = (const float*)d_in[8];
  const float* bnp= (const float*)d_in[9];

  char* ws = (char*)d_ws;
  float* rp  = (float*)ws; ws += (size_t)Bn*Tn*4;
  float* ap  = (float*)ws; ws += (size_t)Bn*Tn*4;
  float* eW1 = (float*)ws; ws += (size_t)Bn*Sn*4;
  float* eW2 = (float*)ws; ws += (size_t)Bn*Sn*4;
  float* lcb = (float*)ws; ws += (size_t)Bn*Tn*4;
  unsigned short* Qbf  = (unsigned short*)ws; ws += (size_t)Bn*Tn*Dn*2;  // 7.86 MB
  unsigned short* WT   = (unsigned short*)ws; ws += (size_t)Dn*Dn*2;     // 2.1 MB
  unsigned short* QWbf = (unsigned short*)ws; ws += (size_t)Bn*Tn*Dn*2;  // 7.86 MB
  unsigned short* Ebf  = (unsigned short*)ws; ws += (size_t)Bn*Sn*Dn*2;  // 33.6 MB
  unsigned short* Pbf = (unsigned short*)ws; ws += (size_t)Bn*Tn*Sn*2;   // 1.97 MB

  conv_fused<<<Bn*Tn + 256 + Bn*Sn/4, 256, 0, stream>>>(
      Q, Wr, br, Wa, ba, Wq, E, Wn, rp, ap, Qbf, WT, Ebf, eW1, eW2);
  gemm_qw_kr<<<(Bn*Tn/64)*(Dn/64) + Bn, 256, 0, stream>>>(
      Qbf, WT, At, eW2, QWbf, lcb);
  g_scan<<<dim3(Bn, Sn/64), 256, 0, stream>>>(
      QWbf, Ebf, At, rp, ap, eW1, lcb, bnp, Pbf);
  gemm_sels<<<dim3(Bn, Dn/64), 256, 0, stream>>>(Pbf, Ebf, (float*)d_out);
}